// Round 6
// baseline (923.124 us; speedup 1.0000x reference)
//
#include <hip/hip_runtime.h>

#define NN 50000
#define EE 100000
#define HIDD 128
#define HH 4
#define CCC 128
#define HCC 512
#define QS 2048            // row stride of fused qkvs buffer (u16 elements)
#define LLL 3
#define SCALE 0.08838834764831845f

typedef unsigned short u16;
typedef unsigned int u32;
typedef __attribute__((ext_vector_type(8))) short bfrag;   // 8 x bf16
typedef __attribute__((ext_vector_type(4))) float fx4;

__device__ __forceinline__ float bfl(u32 u){ return __uint_as_float(u << 16); }
__device__ __forceinline__ float bfh(u32 u){ return __uint_as_float(u & 0xffff0000u); }
__device__ __forceinline__ u16 f2bf(float f){
  u32 u = __float_as_uint(f);
  return (u16)((u + 0x7fffu + ((u >> 16) & 1u)) >> 16);
}
__device__ __forceinline__ u32 pack2(float a, float b){
  return (u32)f2bf(a) | ((u32)f2bf(b) << 16);
}

union bfcvt { bfrag f; uint4 u; };

__global__ __launch_bounds__(256) void kzero(int* p, int n){
  int i = blockIdx.x * 256 + threadIdx.x;
  if (i < n) p[i] = 0;
}

// ---------------- CSR build (once per launch) ----------------
__global__ __launch_bounds__(256) void khist(const int* __restrict__ ei, int* __restrict__ counts){
  int e = blockIdx.x * 256 + threadIdx.x;
  if (e < EE) atomicAdd(&counts[ei[EE + e]], 1);
}

__global__ __launch_bounds__(256) void kscanA(const int* __restrict__ counts, int* __restrict__ bsum){
  __shared__ int sh[256];
  int t = threadIdx.x, i = blockIdx.x * 256 + t;
  sh[t] = (i < NN) ? counts[i] : 0;
  __syncthreads();
  #pragma unroll
  for (int off = 128; off; off >>= 1) {
    if (t < off) sh[t] += sh[t + off];
    __syncthreads();
  }
  if (t == 0) bsum[blockIdx.x] = sh[0];
}

__global__ __launch_bounds__(256) void kscanB(int* __restrict__ bsum, int nb){
  __shared__ int sh[256];
  int t = threadIdx.x;
  int v = (t < nb) ? bsum[t] : 0;
  sh[t] = v;
  __syncthreads();
  #pragma unroll
  for (int off = 1; off < 256; off <<= 1) {
    int a = (t >= off) ? sh[t - off] : 0;
    __syncthreads();
    sh[t] += a;
    __syncthreads();
  }
  if (t < nb) bsum[t] = sh[t] - v;   // exclusive
}

__global__ __launch_bounds__(256) void kscanC(const int* __restrict__ counts,
                                              const int* __restrict__ bsum,
                                              int* __restrict__ rowptr){
  __shared__ int sh[256];
  int t = threadIdx.x, i = blockIdx.x * 256 + t;
  int v = (i < NN) ? counts[i] : 0;
  sh[t] = v;
  __syncthreads();
  #pragma unroll
  for (int off = 1; off < 256; off <<= 1) {
    int a = (t >= off) ? sh[t - off] : 0;
    __syncthreads();
    sh[t] += a;
    __syncthreads();
  }
  if (i <= NN) rowptr[i] = bsum[blockIdx.x] + sh[t] - v;
}

__global__ __launch_bounds__(256) void kscatter(const int* __restrict__ ei,
                                                const float* __restrict__ ea,
                                                const int* __restrict__ rowptr,
                                                int* __restrict__ fill,
                                                int* __restrict__ csr_src,
                                                float* __restrict__ csr_ea){
  int e = blockIdx.x * 256 + threadIdx.x;
  if (e >= EE) return;
  int d = ei[EE + e];
  int pos = rowptr[d] + atomicAdd(&fill[d], 1);
  csr_src[pos] = ei[e];
  csr_ea[pos]  = ea[e];
}

// ---------------- per-layer weight prep -----------------
// Wt[1536][128] bf16 (transposed [Wq|Wk|Wv]), Wpt[128][512] bf16, bias_cat[1536]
__global__ __launch_bounds__(256) void kprep(
    const float* __restrict__ Wq, const float* __restrict__ Wk,
    const float* __restrict__ Wv,
    const float* __restrict__ bq, const float* __restrict__ bk,
    const float* __restrict__ bv,
    const float* __restrict__ Wp,
    u16* __restrict__ Wt, u16* __restrict__ Wpt, float* __restrict__ bias_cat)
{
  int id = blockIdx.x * 256 + threadIdx.x;
  if (id < 1536*128) {
    int n = id >> 7, k = id & 127;
    int m = n >> 9, nc = n & 511;
    const float* W = (m==0)?Wq:(m==1)?Wk:Wv;
    Wt[id] = f2bf(W[(size_t)k*HCC + nc]);
  } else if (id < 1536*128 + 128*512) {
    int j = id - 1536*128;
    int n = j >> 9, k = j & 511;
    Wpt[j] = f2bf(Wp[(size_t)k*HIDD + n]);
  } else if (id < 1536*128 + 128*512 + 1536) {
    int n = id - (1536*128 + 128*512);
    int m = n >> 9, nc = n & 511;
    const float* b = (m==0)?bq:(m==1)?bk:bv;
    bias_cat[n] = b[nc];
  }
}

// kskp: Wskt[b][a] = sum_j Wsk[a][j]*Wp[j][b]  (bf16, B-operand layout)
//       bpe[c] = bp[c] + sum_j bsk[j]*Wp[j][c]
__global__ __launch_bounds__(256) void kskp(
    const float* __restrict__ Wsk, const float* __restrict__ bsk,
    const float* __restrict__ Wp,  const float* __restrict__ bp,
    u16* __restrict__ Wskt, float* __restrict__ bpe)
{
  __shared__ float sh[256];
  int t = threadIdx.x;
  int a = blockIdx.x;
  if (a < 128) {
    int b = t & 127, seg = t >> 7;
    const float* wr = Wsk + (size_t)a*HCC;
    float s = 0.f;
    for (int j = seg*256; j < seg*256 + 256; ++j)
      s += wr[j] * Wp[(size_t)j*HIDD + b];
    sh[t] = s;
    __syncthreads();
    if (t < 128) Wskt[(size_t)t*128 + a] = f2bf(sh[t] + sh[t+128]);
  } else {
    int c = t & 127, seg = t >> 7;
    float s = 0.f;
    for (int j = seg*256; j < seg*256 + 256; ++j)
      s += bsk[j] * Wp[(size_t)j*HIDD + c];
    sh[t] = s;
    __syncthreads();
    if (t < 128) bpe[t] = bp[t] + sh[t] + sh[t+128];
  }
}

// K1: qkvs[N, 0..1536) = bf16( x[N,128] @ Wt^T + bias )   (q|k|v)
// one block per 64 rows; x held in registers; 12 col-chunks of 128
__global__ __launch_bounds__(256) void k1_mfma(
    const float* __restrict__ x, const u16* __restrict__ Wt,
    const float* __restrict__ bias, u16* __restrict__ qkvs)
{
  __shared__ u16 outs[64][136];
  const int t = threadIdx.x;
  const int n0 = blockIdx.x * 64;
  const int wave = t >> 6, lane = t & 63;
  const int lo = lane & 15, hi = lane >> 4;

  // load x fragments directly: a[r][s] covers rows n0+r*16+lo, cols s*32+hi*8..+7
  bfrag a[4][4];
  #pragma unroll
  for (int r = 0; r < 4; ++r) {
    int row = n0 + r*16 + lo;
    const float* xp = x + (size_t)row*HIDD;
    #pragma unroll
    for (int s = 0; s < 4; ++s) {
      bfcvt cv;
      if (row < NN) {
        float4 u = *(const float4*)(xp + s*32 + hi*8);
        float4 w = *(const float4*)(xp + s*32 + hi*8 + 4);
        cv.u = make_uint4(pack2(u.x,u.y), pack2(u.z,u.w),
                          pack2(w.x,w.y), pack2(w.z,w.w));
      } else {
        cv.u = make_uint4(0u,0u,0u,0u);
      }
      a[r][s] = cv.f;
    }
  }

  for (int cc = 0; cc < 12; ++cc) {
    const int cb = cc * 128;
    fx4 acc[4][2] = {};
    #pragma unroll
    for (int s = 0; s < 4; ++s) {
      bfrag b[2];
      #pragma unroll
      for (int c = 0; c < 2; ++c)
        b[c] = *(const bfrag*)(Wt + (size_t)(cb + wave*32 + c*16 + lo)*128 + s*32 + hi*8);
      #pragma unroll
      for (int r = 0; r < 4; ++r)
        #pragma unroll
        for (int c = 0; c < 2; ++c)
          acc[r][c] = __builtin_amdgcn_mfma_f32_16x16x32_bf16(a[r][s], b[c], acc[r][c], 0, 0, 0);
    }

    float bb[2];
    #pragma unroll
    for (int c = 0; c < 2; ++c) bb[c] = bias[cb + wave*32 + c*16 + lo];

    if (cc) __syncthreads();
    #pragma unroll
    for (int r = 0; r < 4; ++r)
      #pragma unroll
      for (int c = 0; c < 2; ++c)
        #pragma unroll
        for (int j = 0; j < 4; ++j)
          outs[r*16 + hi*4 + j][wave*32 + c*16 + lo] = f2bf(acc[r][c][j] + bb[c]);
    __syncthreads();

    #pragma unroll
    for (int i = 0; i < 4; ++i) {
      int f = t + 256*i;
      int r = f >> 4, c8 = (f & 15) * 8;
      if (n0 + r < NN)
        *(uint4*)(qkvs + (size_t)(n0+r)*QS + cb + c8) = *(uint4*)&outs[r][c8];
    }
  }
}

// K23: fused edge attention per dst node (one wave per node).
// conv_row = (Σ p·v[src])/D + ((Σ p·ea)/D)·We   with p = exp(scale·(q·k + ea·qWe))
__global__ __launch_bounds__(256) void k23_fused(
    u16* __restrict__ qkvs, const int* __restrict__ rowptr,
    const int* __restrict__ csr_src, const float* __restrict__ csr_ea,
    const float* __restrict__ We)
{
  int wave = threadIdx.x >> 6, lane = threadIdx.x & 63;
  int n = blockIdx.x * 4 + wave;
  if (n >= NN) return;
  int h = lane >> 4, c0 = (lane & 15) * 8;

  uint4 qa = *(const uint4*)(qkvs + (size_t)n*QS + h*CCC + c0);
  float qf[8] = {bfl(qa.x),bfh(qa.x),bfl(qa.y),bfh(qa.y),
                 bfl(qa.z),bfh(qa.z),bfl(qa.w),bfh(qa.w)};
  float4 w0 = *(const float4*)(We + h*CCC + c0);
  float4 w1 = *(const float4*)(We + h*CCC + c0 + 4);
  float wf[8] = {w0.x,w0.y,w0.z,w0.w,w1.x,w1.y,w1.z,w1.w};

  float qw = qf[0]*wf[0]+qf[1]*wf[1]+qf[2]*wf[2]+qf[3]*wf[3]
           + qf[4]*wf[4]+qf[5]*wf[5]+qf[6]*wf[6]+qf[7]*wf[7];
  #pragma unroll
  for (int off = 8; off; off >>= 1) qw += __shfl_xor(qw, off);

  int beg = rowptr[n], end = rowptr[n+1];
  float accv[8] = {};
  float accp = 0.f, accw = 0.f;

  for (int i = beg; i < end; ++i) {
    int src = csr_src[i];
    float eav = csr_ea[i];
    uint4 ka = *(const uint4*)(qkvs + (size_t)src*QS + 512 + h*CCC + c0);
    float s = qf[0]*bfl(ka.x) + qf[1]*bfh(ka.x)
            + qf[2]*bfl(ka.y) + qf[3]*bfh(ka.y)
            + qf[4]*bfl(ka.z) + qf[5]*bfh(ka.z)
            + qf[6]*bfl(ka.w) + qf[7]*bfh(ka.w);
    #pragma unroll
    for (int off = 8; off; off >>= 1) s += __shfl_xor(s, off);
    float p = expf((s + eav * qw) * SCALE);
    uint4 va = *(const uint4*)(qkvs + (size_t)src*QS + 1024 + h*CCC + c0);
    accv[0] += p*bfl(va.x); accv[1] += p*bfh(va.x);
    accv[2] += p*bfl(va.y); accv[3] += p*bfh(va.y);
    accv[4] += p*bfl(va.z); accv[5] += p*bfh(va.z);
    accv[6] += p*bfl(va.w); accv[7] += p*bfh(va.w);
    accp += p; accw += p*eav;
  }

  float inv = 1.f / (accp + 1e-16f);
  float se  = accw * inv;
  u16* ap = qkvs + (size_t)n*QS + 1536 + h*CCC + c0;
  *(uint4*)ap = make_uint4(
    pack2(accv[0]*inv+se*wf[0], accv[1]*inv+se*wf[1]),
    pack2(accv[2]*inv+se*wf[2], accv[3]*inv+se*wf[3]),
    pack2(accv[4]*inv+se*wf[4], accv[5]*inv+se*wf[5]),
    pack2(accv[6]*inv+se*wf[6], accv[7]*inv+se*wf[7]));
}

// K4: h = elu(conv@Wp + x@Wskp + bpe) ; y = x + h ; LayerNorm (in-register)
__global__ __launch_bounds__(256) void k4_mfma(
    const u16* __restrict__ qkvs, const u16* __restrict__ Wpt,
    const u16* __restrict__ Wskt, const float* __restrict__ bpe,
    const float* __restrict__ gamma, const float* __restrict__ beta,
    const float* x_in, float* x_out)
{
  __shared__ u16 convs[64][136];
  const int t = threadIdx.x;
  const int n0 = blockIdx.x * 64;
  const int wave = t >> 6, lane = t & 63;
  const int lo = lane & 15, hi = lane >> 4;

  fx4 acc[8] = {};

  // skip pass: A = x rows (bf16 on the fly), B = Wskt, K=128
  {
    int row = n0 + wave*16 + lo;
    const float* xp = x_in + (size_t)row*HIDD;
    #pragma unroll
    for (int s = 0; s < 4; ++s) {
      bfcvt cv;
      if (row < NN) {
        float4 u = *(const float4*)(xp + s*32 + hi*8);
        float4 w = *(const float4*)(xp + s*32 + hi*8 + 4);
        cv.u = make_uint4(pack2(u.x,u.y), pack2(u.z,u.w),
                          pack2(w.x,w.y), pack2(w.z,w.w));
      } else {
        cv.u = make_uint4(0u,0u,0u,0u);
      }
      #pragma unroll
      for (int c = 0; c < 8; ++c) {
        bfrag b = *(const bfrag*)(Wskt + (size_t)(c*16 + lo)*128 + s*32 + hi*8);
        acc[c] = __builtin_amdgcn_mfma_f32_16x16x32_bf16(cv.f, b, acc[c], 0, 0, 0);
      }
    }
  }

  // conv passes: K=512 in 4 head chunks
  for (int h = 0; h < 4; ++h) {
    #pragma unroll
    for (int i = 0; i < 4; ++i) {
      int f = t + 256*i;
      int r = f >> 4, c8 = (f & 15) * 8;
      int n = n0 + r;
      uint4 o = make_uint4(0u,0u,0u,0u);
      if (n < NN) o = *(const uint4*)(qkvs + (size_t)n*QS + 1536 + h*CCC + c8);
      *(uint4*)&convs[r][c8] = o;
    }
    __syncthreads();
    #pragma unroll
    for (int s = 0; s < 4; ++s) {
      bfrag a = *(const bfrag*)&convs[wave*16 + lo][s*32 + hi*8];
      #pragma unroll
      for (int c = 0; c < 8; ++c) {
        bfrag b = *(const bfrag*)(Wpt + (size_t)(c*16 + lo)*512 + h*128 + s*32 + hi*8);
        acc[c] = __builtin_amdgcn_mfma_f32_16x16x32_bf16(a, b, acc[c], 0, 0, 0);
      }
    }
    __syncthreads();
  }

  // epilogue: bias + ELU + residual, in-register LayerNorm
  const int rbase = n0 + wave*16 + hi*4;
  float y[8][4];
  #pragma unroll
  for (int c = 0; c < 8; ++c) {
    float bb = bpe[c*16 + lo];
    #pragma unroll
    for (int j = 0; j < 4; ++j) {
      int row = rbase + j;
      float v = acc[c][j] + bb;
      v = v > 0.f ? v : expm1f(v);
      float xv = (row < NN) ? x_in[(size_t)row*HIDD + c*16 + lo] : 0.f;
      y[c][j] = xv + v;
    }
  }
  float mu[4], rs[4];
  #pragma unroll
  for (int j = 0; j < 4; ++j) {
    float s = 0.f, s2 = 0.f;
    #pragma unroll
    for (int c = 0; c < 8; ++c) { s += y[c][j]; s2 += y[c][j]*y[c][j]; }
    #pragma unroll
    for (int off = 8; off; off >>= 1) { s += __shfl_xor(s, off); s2 += __shfl_xor(s2, off); }
    mu[j] = s * (1.f/128.f);
    float var = s2 * (1.f/128.f) - mu[j]*mu[j];
    rs[j] = rsqrtf(var + 1e-5f);
  }
  #pragma unroll
  for (int c = 0; c < 8; ++c) {
    float g  = gamma[c*16 + lo];
    float bt = beta[c*16 + lo];
    #pragma unroll
    for (int j = 0; j < 4; ++j) {
      int row = rbase + j;
      if (row < NN)
        x_out[(size_t)row*HIDD + c*16 + lo] = (y[c][j] - mu[j])*rs[j]*g + bt;
    }
  }
}

extern "C" void kernel_launch(void* const* d_in, const int* in_sizes, int n_in,
                              void* d_out, int out_size, void* d_ws, size_t ws_size,
                              hipStream_t stream)
{
  const float* x    = (const float*)d_in[0];
  const int*   ei   = (const int*)d_in[1];
  const float* ea   = (const float*)d_in[2];
  const float* Wq   = (const float*)d_in[3];
  const float* bq   = (const float*)d_in[4];
  const float* Wk   = (const float*)d_in[5];
  const float* bk   = (const float*)d_in[6];
  const float* Wv   = (const float*)d_in[7];
  const float* bv   = (const float*)d_in[8];
  const float* We   = (const float*)d_in[9];
  const float* Wsk  = (const float*)d_in[10];
  const float* bsk  = (const float*)d_in[11];
  const float* Wp   = (const float*)d_in[12];
  const float* bp   = (const float*)d_in[13];
  const float* gamma= (const float*)d_in[14];
  const float* beta = (const float*)d_in[15];

  char* wsb = (char*)d_ws;
  size_t off = 0;
  auto alloc = [&](size_t bytes) -> void* {
    void* p = wsb + off;
    off += (bytes + 255) & ~(size_t)255;
    return p;
  };
  u16*   qkvs    = (u16*)  alloc((size_t)NN*QS*2);     // 204.8 MB (q|k|v|conv)
  int*   rowptr  = (int*)  alloc((size_t)(NN+1)*4);
  int*   counts  = (int*)  alloc((size_t)NN*4);
  int*   fill    = (int*)  alloc((size_t)NN*4);
  int*   bsum    = (int*)  alloc((size_t)256*4);
  int*   csr_src = (int*)  alloc((size_t)EE*4);
  float* csr_ea  = (float*)alloc((size_t)EE*4);
  u16*   Wt      = (u16*)  alloc((size_t)1536*128*2);
  u16*   Wpt     = (u16*)  alloc((size_t)128*512*2);
  u16*   Wskt    = (u16*)  alloc((size_t)128*128*2);
  float* biasc   = (float*)alloc((size_t)1536*4);
  float* bpe     = (float*)alloc((size_t)128*4);
  float* xio     = (float*)d_out;

  const int gn  = (NN + 255)/256;     // 196
  const int ge  = (EE + 255)/256;
  const int gp  = (1536*128 + 128*512 + 1536 + 255)/256;
  const int g1  = (NN + 63)/64;       // 782
  const int g23 = (NN + 3)/4;
  const int g4  = (NN + 63)/64;

  // ---- CSR build (graph constant across layers) ----
  kzero<<<gn, 256, 0, stream>>>(counts, NN);
  kzero<<<gn, 256, 0, stream>>>(fill, NN);
  khist<<<ge, 256, 0, stream>>>(ei, counts);
  kscanA<<<gn, 256, 0, stream>>>(counts, bsum);
  kscanB<<<1, 256, 0, stream>>>(bsum, gn);
  kscanC<<<gn, 256, 0, stream>>>(counts, bsum, rowptr);
  kscatter<<<ge, 256, 0, stream>>>(ei, ea, rowptr, fill, csr_src, csr_ea);

  for (int l = 0; l < LLL; ++l) {
    const float* Wq_l  = Wq  + (size_t)l*HIDD*HCC;
    const float* Wk_l  = Wk  + (size_t)l*HIDD*HCC;
    const float* Wv_l  = Wv  + (size_t)l*HIDD*HCC;
    const float* Wsk_l = Wsk + (size_t)l*HIDD*HCC;
    const float* bq_l  = bq  + (size_t)l*HCC;
    const float* bk_l  = bk  + (size_t)l*HCC;
    const float* bv_l  = bv  + (size_t)l*HCC;
    const float* bsk_l = bsk + (size_t)l*HCC;
    const float* We_l  = We  + (size_t)l*HCC;
    const float* Wp_l  = Wp  + (size_t)l*HCC*HIDD;
    const float* bp_l  = bp  + (size_t)l*HIDD;
    const float* g_l   = gamma + (size_t)l*HIDD;
    const float* b_l   = beta  + (size_t)l*HIDD;

    const float* xin = (l == 0) ? x : xio;

    kprep<<<gp, 256, 0, stream>>>(Wq_l, Wk_l, Wv_l, bq_l, bk_l, bv_l,
                                  Wp_l, Wt, Wpt, biasc);
    kskp<<<129, 256, 0, stream>>>(Wsk_l, bsk_l, Wp_l, bp_l, Wskt, bpe);
    k1_mfma<<<g1, 256, 0, stream>>>(xin, Wt, biasc, qkvs);
    k23_fused<<<g23, 256, 0, stream>>>(qkvs, rowptr, csr_src, csr_ea, We_l);
    k4_mfma<<<g4, 256, 0, stream>>>(qkvs, Wpt, Wskt, bpe, g_l, b_l, xin, xio);
  }
}

// Round 7
// 905.843 us; speedup vs baseline: 1.0191x; 1.0191x over previous
//
#include <hip/hip_runtime.h>

#define NN 50000
#define EE 100000
#define HIDD 128
#define HH 4
#define CCC 128
#define HCC 512
#define QS 2048            // row stride of fused qkvs buffer (u16 elements)
#define LLL 3
#define SCALE 0.08838834764831845f

typedef unsigned short u16;
typedef unsigned int u32;
typedef __attribute__((ext_vector_type(8))) short bfrag;   // 8 x bf16
typedef __attribute__((ext_vector_type(4))) float fx4;

__device__ __forceinline__ float bfl(u32 u){ return __uint_as_float(u << 16); }
__device__ __forceinline__ float bfh(u32 u){ return __uint_as_float(u & 0xffff0000u); }
__device__ __forceinline__ u16 f2bf(float f){
  u32 u = __float_as_uint(f);
  return (u16)((u + 0x7fffu + ((u >> 16) & 1u)) >> 16);
}
__device__ __forceinline__ u32 pack2(float a, float b){
  return (u32)f2bf(a) | ((u32)f2bf(b) << 16);
}

union bfcvt { bfrag f; uint4 u; };

__global__ __launch_bounds__(256) void kzero(int* p, int n){
  int i = blockIdx.x * 256 + threadIdx.x;
  if (i < n) p[i] = 0;
}

// ---------------- CSR build (once per launch) ----------------
__global__ __launch_bounds__(256) void khist(const int* __restrict__ ei, int* __restrict__ counts){
  int e = blockIdx.x * 256 + threadIdx.x;
  if (e < EE) atomicAdd(&counts[ei[EE + e]], 1);
}

__global__ __launch_bounds__(256) void kscanA(const int* __restrict__ counts, int* __restrict__ bsum){
  __shared__ int sh[256];
  int t = threadIdx.x, i = blockIdx.x * 256 + t;
  sh[t] = (i < NN) ? counts[i] : 0;
  __syncthreads();
  #pragma unroll
  for (int off = 128; off; off >>= 1) {
    if (t < off) sh[t] += sh[t + off];
    __syncthreads();
  }
  if (t == 0) bsum[blockIdx.x] = sh[0];
}

__global__ __launch_bounds__(256) void kscanB(int* __restrict__ bsum, int nb){
  __shared__ int sh[256];
  int t = threadIdx.x;
  int v = (t < nb) ? bsum[t] : 0;
  sh[t] = v;
  __syncthreads();
  #pragma unroll
  for (int off = 1; off < 256; off <<= 1) {
    int a = (t >= off) ? sh[t - off] : 0;
    __syncthreads();
    sh[t] += a;
    __syncthreads();
  }
  if (t < nb) bsum[t] = sh[t] - v;   // exclusive
}

__global__ __launch_bounds__(256) void kscanC(const int* __restrict__ counts,
                                              const int* __restrict__ bsum,
                                              int* __restrict__ rowptr){
  __shared__ int sh[256];
  int t = threadIdx.x, i = blockIdx.x * 256 + t;
  int v = (i < NN) ? counts[i] : 0;
  sh[t] = v;
  __syncthreads();
  #pragma unroll
  for (int off = 1; off < 256; off <<= 1) {
    int a = (t >= off) ? sh[t - off] : 0;
    __syncthreads();
    sh[t] += a;
    __syncthreads();
  }
  if (i <= NN) rowptr[i] = bsum[blockIdx.x] + sh[t] - v;
}

__global__ __launch_bounds__(256) void kscatter(const int* __restrict__ ei,
                                                const float* __restrict__ ea,
                                                const int* __restrict__ rowptr,
                                                int* __restrict__ fill,
                                                int* __restrict__ csr_src,
                                                float* __restrict__ csr_ea){
  int e = blockIdx.x * 256 + threadIdx.x;
  if (e >= EE) return;
  int d = ei[EE + e];
  int pos = rowptr[d] + atomicAdd(&fill[d], 1);
  csr_src[pos] = ei[e];
  csr_ea[pos]  = ea[e];
}

// ---------------- per-layer weight prep -----------------
// Wt[1536][128] bf16 (transposed [Wq|Wk|Wv]), Wpt[128][512] bf16, bias_cat[1536]
__global__ __launch_bounds__(256) void kprep(
    const float* __restrict__ Wq, const float* __restrict__ Wk,
    const float* __restrict__ Wv,
    const float* __restrict__ bq, const float* __restrict__ bk,
    const float* __restrict__ bv,
    const float* __restrict__ Wp,
    u16* __restrict__ Wt, u16* __restrict__ Wpt, float* __restrict__ bias_cat)
{
  int id = blockIdx.x * 256 + threadIdx.x;
  if (id < 1536*128) {
    int n = id >> 7, k = id & 127;
    int m = n >> 9, nc = n & 511;
    const float* W = (m==0)?Wq:(m==1)?Wk:Wv;
    Wt[id] = f2bf(W[(size_t)k*HCC + nc]);
  } else if (id < 1536*128 + 128*512) {
    int j = id - 1536*128;
    int n = j >> 9, k = j & 511;
    Wpt[j] = f2bf(Wp[(size_t)k*HIDD + n]);
  } else if (id < 1536*128 + 128*512 + 1536) {
    int n = id - (1536*128 + 128*512);
    int m = n >> 9, nc = n & 511;
    const float* b = (m==0)?bq:(m==1)?bk:bv;
    bias_cat[n] = b[nc];
  }
}

// kskp: Wskt[b][a] = sum_j Wsk[a][j]*Wp[j][b]  (bf16, B-operand layout)
//       bpe[c] = bp[c] + sum_j bsk[j]*Wp[j][c]
__global__ __launch_bounds__(256) void kskp(
    const float* __restrict__ Wsk, const float* __restrict__ bsk,
    const float* __restrict__ Wp,  const float* __restrict__ bp,
    u16* __restrict__ Wskt, float* __restrict__ bpe)
{
  __shared__ float sh[256];
  int t = threadIdx.x;
  int a = blockIdx.x;
  if (a < 128) {
    int b = t & 127, seg = t >> 7;
    const float* wr = Wsk + (size_t)a*HCC;
    float s = 0.f;
    for (int j = seg*256; j < seg*256 + 256; ++j)
      s += wr[j] * Wp[(size_t)j*HIDD + b];
    sh[t] = s;
    __syncthreads();
    if (t < 128) Wskt[(size_t)t*128 + a] = f2bf(sh[t] + sh[t+128]);
  } else {
    int c = t & 127, seg = t >> 7;
    float s = 0.f;
    for (int j = seg*256; j < seg*256 + 256; ++j)
      s += bsk[j] * Wp[(size_t)j*HIDD + c];
    sh[t] = s;
    __syncthreads();
    if (t < 128) bpe[t] = bp[t] + sh[t] + sh[t+128];
  }
}

// K1: qkvs[N, 0..1536) = bf16( x[N,128] @ Wt^T + bias )   (q|k|v)
// 64 rows per block; x in registers; 12 col-chunks of 128.
// NO barriers: each wave packs its own 64x32 output slice through private LDS.
__global__ __launch_bounds__(256) void k1_mfma(
    const float* __restrict__ x, const u16* __restrict__ Wt,
    const float* __restrict__ bias, u16* __restrict__ qkvs)
{
  __shared__ u16 outs[4][64][40];   // per-wave slice, pitch 40 (16B-aligned rows)
  const int t = threadIdx.x;
  const int n0 = blockIdx.x * 64;
  const int wave = t >> 6, lane = t & 63;
  const int lo = lane & 15, hi = lane >> 4;

  // x fragments: a[r][s] covers rows n0+r*16+lo, k-cols s*32+hi*8..+7
  bfrag a[4][4];
  #pragma unroll
  for (int r = 0; r < 4; ++r) {
    int row = n0 + r*16 + lo;
    const float* xp = x + (size_t)row*HIDD;
    #pragma unroll
    for (int s = 0; s < 4; ++s) {
      bfcvt cv;
      if (row < NN) {
        float4 u = *(const float4*)(xp + s*32 + hi*8);
        float4 w = *(const float4*)(xp + s*32 + hi*8 + 4);
        cv.u = make_uint4(pack2(u.x,u.y), pack2(u.z,u.w),
                          pack2(w.x,w.y), pack2(w.z,w.w));
      } else {
        cv.u = make_uint4(0u,0u,0u,0u);
      }
      a[r][s] = cv.f;
    }
  }

  for (int cc = 0; cc < 12; ++cc) {
    const int cb = cc * 128;
    fx4 acc[4][2] = {};
    #pragma unroll
    for (int s = 0; s < 4; ++s) {
      bfrag b[2];
      #pragma unroll
      for (int c = 0; c < 2; ++c)
        b[c] = *(const bfrag*)(Wt + (size_t)(cb + wave*32 + c*16 + lo)*128 + s*32 + hi*8);
      #pragma unroll
      for (int r = 0; r < 4; ++r)
        #pragma unroll
        for (int c = 0; c < 2; ++c)
          acc[r][c] = __builtin_amdgcn_mfma_f32_16x16x32_bf16(a[r][s], b[c], acc[r][c], 0, 0, 0);
    }

    float bb[2];
    #pragma unroll
    for (int c = 0; c < 2; ++c) bb[c] = bias[cb + wave*32 + c*16 + lo];

    // pack into this wave's private LDS slice (in-order per wave; no barrier)
    #pragma unroll
    for (int r = 0; r < 4; ++r)
      #pragma unroll
      for (int c = 0; c < 2; ++c)
        #pragma unroll
        for (int j = 0; j < 4; ++j)
          outs[wave][r*16 + hi*4 + j][c*16 + lo] = f2bf(acc[r][c][j] + bb[c]);

    // coalesced 16B stores: 64 rows x 32 cols per wave = 256 uint4
    #pragma unroll
    for (int i = 0; i < 4; ++i) {
      int f = lane + 64*i;
      int r = f >> 2, seg = f & 3;
      if (n0 + r < NN)
        *(uint4*)(qkvs + (size_t)(n0+r)*QS + cb + wave*32 + seg*8)
            = *(uint4*)&outs[wave][r][seg*8];
    }
  }
}

// K23: fused edge attention per dst node (one wave per node).
// conv_row = (Σ p·v[src])/D + ((Σ p·ea)/D)·We   with p = exp(scale·(q·k + ea·qWe))
__global__ __launch_bounds__(256) void k23_fused(
    u16* __restrict__ qkvs, const int* __restrict__ rowptr,
    const int* __restrict__ csr_src, const float* __restrict__ csr_ea,
    const float* __restrict__ We)
{
  int wave = threadIdx.x >> 6, lane = threadIdx.x & 63;
  int n = blockIdx.x * 4 + wave;
  if (n >= NN) return;
  int h = lane >> 4, c0 = (lane & 15) * 8;

  uint4 qa = *(const uint4*)(qkvs + (size_t)n*QS + h*CCC + c0);
  float qf[8] = {bfl(qa.x),bfh(qa.x),bfl(qa.y),bfh(qa.y),
                 bfl(qa.z),bfh(qa.z),bfl(qa.w),bfh(qa.w)};
  float4 w0 = *(const float4*)(We + h*CCC + c0);
  float4 w1 = *(const float4*)(We + h*CCC + c0 + 4);
  float wf[8] = {w0.x,w0.y,w0.z,w0.w,w1.x,w1.y,w1.z,w1.w};

  float qw = qf[0]*wf[0]+qf[1]*wf[1]+qf[2]*wf[2]+qf[3]*wf[3]
           + qf[4]*wf[4]+qf[5]*wf[5]+qf[6]*wf[6]+qf[7]*wf[7];
  #pragma unroll
  for (int off = 8; off; off >>= 1) qw += __shfl_xor(qw, off);

  int beg = rowptr[n], end = rowptr[n+1];
  float accv[8] = {};
  float accp = 0.f, accw = 0.f;

  for (int i = beg; i < end; ++i) {
    int src = csr_src[i];
    float eav = csr_ea[i];
    uint4 ka = *(const uint4*)(qkvs + (size_t)src*QS + 512 + h*CCC + c0);
    float s = qf[0]*bfl(ka.x) + qf[1]*bfh(ka.x)
            + qf[2]*bfl(ka.y) + qf[3]*bfh(ka.y)
            + qf[4]*bfl(ka.z) + qf[5]*bfh(ka.z)
            + qf[6]*bfl(ka.w) + qf[7]*bfh(ka.w);
    #pragma unroll
    for (int off = 8; off; off >>= 1) s += __shfl_xor(s, off);
    float p = expf((s + eav * qw) * SCALE);
    uint4 va = *(const uint4*)(qkvs + (size_t)src*QS + 1024 + h*CCC + c0);
    accv[0] += p*bfl(va.x); accv[1] += p*bfh(va.x);
    accv[2] += p*bfl(va.y); accv[3] += p*bfh(va.y);
    accv[4] += p*bfl(va.z); accv[5] += p*bfh(va.z);
    accv[6] += p*bfl(va.w); accv[7] += p*bfh(va.w);
    accp += p; accw += p*eav;
  }

  float inv = 1.f / (accp + 1e-16f);
  float se  = accw * inv;
  u16* ap = qkvs + (size_t)n*QS + 1536 + h*CCC + c0;
  *(uint4*)ap = make_uint4(
    pack2(accv[0]*inv+se*wf[0], accv[1]*inv+se*wf[1]),
    pack2(accv[2]*inv+se*wf[2], accv[3]*inv+se*wf[3]),
    pack2(accv[4]*inv+se*wf[4], accv[5]*inv+se*wf[5]),
    pack2(accv[6]*inv+se*wf[6], accv[7]*inv+se*wf[7]));
}

// K4: h = elu(conv@Wp + x@Wskp + bpe) ; y = x + h ; LayerNorm (in-register)
// NO barriers: each wave owns 16 rows; conv A-fragments read directly from
// global; stores packed through per-wave private LDS.
__global__ __launch_bounds__(256) void k4_mfma(
    const u16* __restrict__ qkvs, const u16* __restrict__ Wpt,
    const u16* __restrict__ Wskt, const float* __restrict__ bpe,
    const float* __restrict__ gamma, const float* __restrict__ beta,
    const float* x_in, float* x_out)
{
  __shared__ float yt[4][16][132];
  const int t = threadIdx.x;
  const int wave = t >> 6, lane = t & 63;
  const int lo = lane & 15, hi = lane >> 4;
  const int r0 = blockIdx.x * 64 + wave * 16;   // wave's first row

  fx4 acc[8] = {};

  // skip pass: A = x rows (bf16 on the fly), B = Wskt, K=128
  {
    int row = r0 + lo;
    const float* xp = x_in + (size_t)row*HIDD;
    #pragma unroll
    for (int s = 0; s < 4; ++s) {
      bfcvt cv;
      if (row < NN) {
        float4 u = *(const float4*)(xp + s*32 + hi*8);
        float4 w = *(const float4*)(xp + s*32 + hi*8 + 4);
        cv.u = make_uint4(pack2(u.x,u.y), pack2(u.z,u.w),
                          pack2(w.x,w.y), pack2(w.z,w.w));
      } else {
        cv.u = make_uint4(0u,0u,0u,0u);
      }
      #pragma unroll
      for (int c = 0; c < 8; ++c) {
        bfrag b = *(const bfrag*)(Wskt + (size_t)(c*16 + lo)*128 + s*32 + hi*8);
        acc[c] = __builtin_amdgcn_mfma_f32_16x16x32_bf16(cv.f, b, acc[c], 0, 0, 0);
      }
    }
  }

  // conv passes: K=512 in 4 head chunks, A read directly from global
  for (int h = 0; h < 4; ++h) {
    int row = r0 + lo;
    const u16* cp = qkvs + (size_t)row*QS + 1536 + h*CCC;
    #pragma unroll
    for (int s = 0; s < 4; ++s) {
      bfcvt cv;
      if (row < NN) cv.u = *(const uint4*)(cp + s*32 + hi*8);
      else          cv.u = make_uint4(0u,0u,0u,0u);
      #pragma unroll
      for (int c = 0; c < 8; ++c) {
        bfrag b = *(const bfrag*)(Wpt + (size_t)(c*16 + lo)*512 + h*128 + s*32 + hi*8);
        acc[c] = __builtin_amdgcn_mfma_f32_16x16x32_bf16(cv.f, b, acc[c], 0, 0, 0);
      }
    }
  }

  // epilogue: bias + ELU + residual, in-register LayerNorm
  const int rbase = r0 + hi*4;
  float y[8][4];
  #pragma unroll
  for (int c = 0; c < 8; ++c) {
    float bb = bpe[c*16 + lo];
    #pragma unroll
    for (int j = 0; j < 4; ++j) {
      int row = rbase + j;
      float v = acc[c][j] + bb;
      v = v > 0.f ? v : expm1f(v);
      float xv = (row < NN) ? x_in[(size_t)row*HIDD + c*16 + lo] : 0.f;
      y[c][j] = xv + v;
    }
  }
  float mu[4], rs[4];
  #pragma unroll
  for (int j = 0; j < 4; ++j) {
    float s = 0.f, s2 = 0.f;
    #pragma unroll
    for (int c = 0; c < 8; ++c) { s += y[c][j]; s2 += y[c][j]*y[c][j]; }
    #pragma unroll
    for (int off = 8; off; off >>= 1) { s += __shfl_xor(s, off); s2 += __shfl_xor(s2, off); }
    mu[j] = s * (1.f/128.f);
    float var = s2 * (1.f/128.f) - mu[j]*mu[j];
    rs[j] = rsqrtf(var + 1e-5f);
  }

  // normalized values -> per-wave LDS slice -> coalesced float4 stores
  #pragma unroll
  for (int c = 0; c < 8; ++c) {
    float g  = gamma[c*16 + lo];
    float bt = beta[c*16 + lo];
    #pragma unroll
    for (int j = 0; j < 4; ++j)
      yt[wave][hi*4 + j][c*16 + lo] = (y[c][j] - mu[j])*rs[j]*g + bt;
  }
  #pragma unroll
  for (int i = 0; i < 8; ++i) {
    int f = lane + 64*i;           // 16*128/4 = 512 float4 per wave
    int r = f >> 5, c4 = (f & 31) * 4;
    int row = r0 + r;
    if (row < NN)
      *(float4*)(x_out + (size_t)row*HIDD + c4) = *(float4*)&yt[wave][r][c4];
  }
}

extern "C" void kernel_launch(void* const* d_in, const int* in_sizes, int n_in,
                              void* d_out, int out_size, void* d_ws, size_t ws_size,
                              hipStream_t stream)
{
  const float* x    = (const float*)d_in[0];
  const int*   ei   = (const int*)d_in[1];
  const float* ea   = (const float*)d_in[2];
  const float* Wq   = (const float*)d_in[3];
  const float* bq   = (const float*)d_in[4];
  const float* Wk   = (const float*)d_in[5];
  const float* bk   = (const float*)d_in[6];
  const float* Wv   = (const float*)d_in[7];
  const float* bv   = (const float*)d_in[8];
  const float* We   = (const float*)d_in[9];
  const float* Wsk  = (const float*)d_in[10];
  const float* bsk  = (const float*)d_in[11];
  const float* Wp   = (const float*)d_in[12];
  const float* bp   = (const float*)d_in[13];
  const float* gamma= (const float*)d_in[14];
  const float* beta = (const float*)d_in[15];

  char* wsb = (char*)d_ws;
  size_t off = 0;
  auto alloc = [&](size_t bytes) -> void* {
    void* p = wsb + off;
    off += (bytes + 255) & ~(size_t)255;
    return p;
  };
  u16*   qkvs    = (u16*)  alloc((size_t)NN*QS*2);     // 204.8 MB (q|k|v|conv)
  int*   rowptr  = (int*)  alloc((size_t)(NN+1)*4);
  int*   counts  = (int*)  alloc((size_t)NN*4);
  int*   fill    = (int*)  alloc((size_t)NN*4);
  int*   bsum    = (int*)  alloc((size_t)256*4);
  int*   csr_src = (int*)  alloc((size_t)EE*4);
  float* csr_ea  = (float*)alloc((size_t)EE*4);
  u16*   Wt      = (u16*)  alloc((size_t)1536*128*2);
  u16*   Wpt     = (u16*)  alloc((size_t)128*512*2);
  u16*   Wskt    = (u16*)  alloc((size_t)128*128*2);
  float* biasc   = (float*)alloc((size_t)1536*4);
  float* bpe     = (float*)alloc((size_t)128*4);
  float* xio     = (float*)d_out;

  const int gn  = (NN + 255)/256;     // 196
  const int ge  = (EE + 255)/256;
  const int gp  = (1536*128 + 128*512 + 1536 + 255)/256;
  const int g1  = (NN + 63)/64;       // 782
  const int g23 = (NN + 3)/4;
  const int g4  = (NN + 63)/64;

  // ---- CSR build (graph constant across layers) ----
  kzero<<<gn, 256, 0, stream>>>(counts, NN);
  kzero<<<gn, 256, 0, stream>>>(fill, NN);
  khist<<<ge, 256, 0, stream>>>(ei, counts);
  kscanA<<<gn, 256, 0, stream>>>(counts, bsum);
  kscanB<<<1, 256, 0, stream>>>(bsum, gn);
  kscanC<<<gn, 256, 0, stream>>>(counts, bsum, rowptr);
  kscatter<<<ge, 256, 0, stream>>>(ei, ea, rowptr, fill, csr_src, csr_ea);

  for (int l = 0; l < LLL; ++l) {
    const float* Wq_l  = Wq  + (size_t)l*HIDD*HCC;
    const float* Wk_l  = Wk  + (size_t)l*HIDD*HCC;
    const float* Wv_l  = Wv  + (size_t)l*HIDD*HCC;
    const float* Wsk_l = Wsk + (size_t)l*HIDD*HCC;
    const float* bq_l  = bq  + (size_t)l*HCC;
    const float* bk_l  = bk  + (size_t)l*HCC;
    const float* bv_l  = bv  + (size_t)l*HCC;
    const float* bsk_l = bsk + (size_t)l*HCC;
    const float* We_l  = We  + (size_t)l*HCC;
    const float* Wp_l  = Wp  + (size_t)l*HCC*HIDD;
    const float* bp_l  = bp  + (size_t)l*HIDD;
    const float* g_l   = gamma + (size_t)l*HIDD;
    const float* b_l   = beta  + (size_t)l*HIDD;

    const float* xin = (l == 0) ? x : xio;

    kprep<<<gp, 256, 0, stream>>>(Wq_l, Wk_l, Wv_l, bq_l, bk_l, bv_l,
                                  Wp_l, Wt, Wpt, biasc);
    kskp<<<129, 256, 0, stream>>>(Wsk_l, bsk_l, Wp_l, bp_l, Wskt, bpe);
    k1_mfma<<<g1, 256, 0, stream>>>(xin, Wt, biasc, qkvs);
    k23_fused<<<g23, 256, 0, stream>>>(qkvs, rowptr, csr_src, csr_ea, We_l);
    k4_mfma<<<g4, 256, 0, stream>>>(qkvs, Wpt, Wskt, bpe, g_l, b_l, xin, xio);
  }
}

// Round 8
// 835.403 us; speedup vs baseline: 1.1050x; 1.0843x over previous
//
#include <hip/hip_runtime.h>

#define NN 50000
#define EE 100000
#define HIDD 128
#define HH 4
#define CCC 128
#define HCC 512
#define QS 2048            // row stride of fused qkvs buffer (u16 elements)
#define LLL 3
#define SCALE 0.08838834764831845f

typedef unsigned short u16;
typedef unsigned int u32;
typedef __attribute__((ext_vector_type(8))) short bfrag;   // 8 x bf16
typedef __attribute__((ext_vector_type(4))) float fx4;

__device__ __forceinline__ float bfl(u32 u){ return __uint_as_float(u << 16); }
__device__ __forceinline__ float bfh(u32 u){ return __uint_as_float(u & 0xffff0000u); }
__device__ __forceinline__ u16 f2bf(float f){
  u32 u = __float_as_uint(f);
  return (u16)((u + 0x7fffu + ((u >> 16) & 1u)) >> 16);
}
__device__ __forceinline__ u32 pack2(float a, float b){
  return (u32)f2bf(a) | ((u32)f2bf(b) << 16);
}

union bfcvt { bfrag f; uint4 u; };

__global__ __launch_bounds__(256) void kzero(int* p, int n){
  int i = blockIdx.x * 256 + threadIdx.x;
  if (i < n) p[i] = 0;
}

// ---------------- CSR build (once per launch) ----------------
__global__ __launch_bounds__(256) void khist(const int* __restrict__ ei, int* __restrict__ counts){
  int e = blockIdx.x * 256 + threadIdx.x;
  if (e < EE) atomicAdd(&counts[ei[EE + e]], 1);
}

__global__ __launch_bounds__(256) void kscanA(const int* __restrict__ counts, int* __restrict__ bsum){
  __shared__ int sh[256];
  int t = threadIdx.x, i = blockIdx.x * 256 + t;
  sh[t] = (i < NN) ? counts[i] : 0;
  __syncthreads();
  #pragma unroll
  for (int off = 128; off; off >>= 1) {
    if (t < off) sh[t] += sh[t + off];
    __syncthreads();
  }
  if (t == 0) bsum[blockIdx.x] = sh[0];
}

__global__ __launch_bounds__(256) void kscanB(int* __restrict__ bsum, int nb){
  __shared__ int sh[256];
  int t = threadIdx.x;
  int v = (t < nb) ? bsum[t] : 0;
  sh[t] = v;
  __syncthreads();
  #pragma unroll
  for (int off = 1; off < 256; off <<= 1) {
    int a = (t >= off) ? sh[t - off] : 0;
    __syncthreads();
    sh[t] += a;
    __syncthreads();
  }
  if (t < nb) bsum[t] = sh[t] - v;   // exclusive
}

__global__ __launch_bounds__(256) void kscanC(const int* __restrict__ counts,
                                              const int* __restrict__ bsum,
                                              int* __restrict__ rowptr){
  __shared__ int sh[256];
  int t = threadIdx.x, i = blockIdx.x * 256 + t;
  int v = (i < NN) ? counts[i] : 0;
  sh[t] = v;
  __syncthreads();
  #pragma unroll
  for (int off = 1; off < 256; off <<= 1) {
    int a = (t >= off) ? sh[t - off] : 0;
    __syncthreads();
    sh[t] += a;
    __syncthreads();
  }
  if (i <= NN) rowptr[i] = bsum[blockIdx.x] + sh[t] - v;
}

__global__ __launch_bounds__(256) void kscatter(const int* __restrict__ ei,
                                                const float* __restrict__ ea,
                                                const int* __restrict__ rowptr,
                                                int* __restrict__ fill,
                                                int* __restrict__ csr_src,
                                                float* __restrict__ csr_ea){
  int e = blockIdx.x * 256 + threadIdx.x;
  if (e >= EE) return;
  int d = ei[EE + e];
  int pos = rowptr[d] + atomicAdd(&fill[d], 1);
  csr_src[pos] = ei[e];
  csr_ea[pos]  = ea[e];
}

// ---------------- per-layer weight prep -----------------
// Wt[1536][128] bf16 (transposed [Wq|Wk|Wv]), Wpt[128][512] bf16, bias_cat[1536]
__global__ __launch_bounds__(256) void kprep(
    const float* __restrict__ Wq, const float* __restrict__ Wk,
    const float* __restrict__ Wv,
    const float* __restrict__ bq, const float* __restrict__ bk,
    const float* __restrict__ bv,
    const float* __restrict__ Wp,
    u16* __restrict__ Wt, u16* __restrict__ Wpt, float* __restrict__ bias_cat)
{
  int id = blockIdx.x * 256 + threadIdx.x;
  if (id < 1536*128) {
    int n = id >> 7, k = id & 127;
    int m = n >> 9, nc = n & 511;
    const float* W = (m==0)?Wq:(m==1)?Wk:Wv;
    Wt[id] = f2bf(W[(size_t)k*HCC + nc]);
  } else if (id < 1536*128 + 128*512) {
    int j = id - 1536*128;
    int n = j >> 9, k = j & 511;
    Wpt[j] = f2bf(Wp[(size_t)k*HIDD + n]);
  } else if (id < 1536*128 + 128*512 + 1536) {
    int n = id - (1536*128 + 128*512);
    int m = n >> 9, nc = n & 511;
    const float* b = (m==0)?bq:(m==1)?bk:bv;
    bias_cat[n] = b[nc];
  }
}

// kskp: Wskt[b][a] = sum_j Wsk[a][j]*Wp[j][b]  (bf16, B-operand layout)
//       bpe[c] = bp[c] + sum_j bsk[j]*Wp[j][c]
__global__ __launch_bounds__(256) void kskp(
    const float* __restrict__ Wsk, const float* __restrict__ bsk,
    const float* __restrict__ Wp,  const float* __restrict__ bp,
    u16* __restrict__ Wskt, float* __restrict__ bpe)
{
  __shared__ float sh[256];
  int t = threadIdx.x;
  int a = blockIdx.x;
  if (a < 128) {
    int b = t & 127, seg = t >> 7;
    const float* wr = Wsk + (size_t)a*HCC;
    float s = 0.f;
    for (int j = seg*256; j < seg*256 + 256; ++j)
      s += wr[j] * Wp[(size_t)j*HIDD + b];
    sh[t] = s;
    __syncthreads();
    if (t < 128) Wskt[(size_t)t*128 + a] = f2bf(sh[t] + sh[t+128]);
  } else {
    int c = t & 127, seg = t >> 7;
    float s = 0.f;
    for (int j = seg*256; j < seg*256 + 256; ++j)
      s += bsk[j] * Wp[(size_t)j*HIDD + c];
    sh[t] = s;
    __syncthreads();
    if (t < 128) bpe[t] = bp[t] + sh[t] + sh[t+128];
  }
}

// K1: qkvs[N, 0..1536) = bf16( x[N,128] @ Wt^T + bias )   (q|k|v)
// 64 rows per block; x in registers; 12 col-chunks of 128.
// NO barriers: each wave packs its own 64x32 output slice through private LDS.
__global__ __launch_bounds__(256) void k1_mfma(
    const float* __restrict__ x, const u16* __restrict__ Wt,
    const float* __restrict__ bias, u16* __restrict__ qkvs)
{
  __shared__ u16 outs[4][64][40];   // per-wave slice, pitch 40 (16B-aligned rows)
  const int t = threadIdx.x;
  const int n0 = blockIdx.x * 64;
  const int wave = t >> 6, lane = t & 63;
  const int lo = lane & 15, hi = lane >> 4;

  // x fragments: a[r][s] covers rows n0+r*16+lo, k-cols s*32+hi*8..+7
  bfrag a[4][4];
  #pragma unroll
  for (int r = 0; r < 4; ++r) {
    int row = n0 + r*16 + lo;
    const float* xp = x + (size_t)row*HIDD;
    #pragma unroll
    for (int s = 0; s < 4; ++s) {
      bfcvt cv;
      if (row < NN) {
        float4 u = *(const float4*)(xp + s*32 + hi*8);
        float4 w = *(const float4*)(xp + s*32 + hi*8 + 4);
        cv.u = make_uint4(pack2(u.x,u.y), pack2(u.z,u.w),
                          pack2(w.x,w.y), pack2(w.z,w.w));
      } else {
        cv.u = make_uint4(0u,0u,0u,0u);
      }
      a[r][s] = cv.f;
    }
  }

  for (int cc = 0; cc < 12; ++cc) {
    const int cb = cc * 128;
    fx4 acc[4][2] = {};
    #pragma unroll
    for (int s = 0; s < 4; ++s) {
      bfrag b[2];
      #pragma unroll
      for (int c = 0; c < 2; ++c)
        b[c] = *(const bfrag*)(Wt + (size_t)(cb + wave*32 + c*16 + lo)*128 + s*32 + hi*8);
      #pragma unroll
      for (int r = 0; r < 4; ++r)
        #pragma unroll
        for (int c = 0; c < 2; ++c)
          acc[r][c] = __builtin_amdgcn_mfma_f32_16x16x32_bf16(a[r][s], b[c], acc[r][c], 0, 0, 0);
    }

    float bb[2];
    #pragma unroll
    for (int c = 0; c < 2; ++c) bb[c] = bias[cb + wave*32 + c*16 + lo];

    // pack into this wave's private LDS slice (in-order per wave; no barrier)
    #pragma unroll
    for (int r = 0; r < 4; ++r)
      #pragma unroll
      for (int c = 0; c < 2; ++c)
        #pragma unroll
        for (int j = 0; j < 4; ++j)
          outs[wave][r*16 + hi*4 + j][c*16 + lo] = f2bf(acc[r][c][j] + bb[c]);

    // coalesced 16B stores: 64 rows x 32 cols per wave = 256 uint4
    #pragma unroll
    for (int i = 0; i < 4; ++i) {
      int f = lane + 64*i;
      int r = f >> 2, seg = f & 3;
      if (n0 + r < NN)
        *(uint4*)(qkvs + (size_t)(n0+r)*QS + cb + wave*32 + seg*8)
            = *(uint4*)&outs[wave][r][seg*8];
    }
  }
}

// K23: fused edge attention per dst node (one wave per node).
// conv_row = (Σ p·v[src])/D + ((Σ p·ea)/D)·We   with p = exp(scale·(q·k + ea·qWe))
__global__ __launch_bounds__(256) void k23_fused(
    u16* __restrict__ qkvs, const int* __restrict__ rowptr,
    const int* __restrict__ csr_src, const float* __restrict__ csr_ea,
    const float* __restrict__ We)
{
  int wave = threadIdx.x >> 6, lane = threadIdx.x & 63;
  int n = blockIdx.x * 4 + wave;
  if (n >= NN) return;
  int h = lane >> 4, c0 = (lane & 15) * 8;

  uint4 qa = *(const uint4*)(qkvs + (size_t)n*QS + h*CCC + c0);
  float qf[8] = {bfl(qa.x),bfh(qa.x),bfl(qa.y),bfh(qa.y),
                 bfl(qa.z),bfh(qa.z),bfl(qa.w),bfh(qa.w)};
  float4 w0 = *(const float4*)(We + h*CCC + c0);
  float4 w1 = *(const float4*)(We + h*CCC + c0 + 4);
  float wf[8] = {w0.x,w0.y,w0.z,w0.w,w1.x,w1.y,w1.z,w1.w};

  float qw = qf[0]*wf[0]+qf[1]*wf[1]+qf[2]*wf[2]+qf[3]*wf[3]
           + qf[4]*wf[4]+qf[5]*wf[5]+qf[6]*wf[6]+qf[7]*wf[7];
  #pragma unroll
  for (int off = 8; off; off >>= 1) qw += __shfl_xor(qw, off);

  int beg = rowptr[n], end = rowptr[n+1];
  float accv[8] = {};
  float accp = 0.f, accw = 0.f;

  for (int i = beg; i < end; ++i) {
    int src = csr_src[i];
    float eav = csr_ea[i];
    uint4 ka = *(const uint4*)(qkvs + (size_t)src*QS + 512 + h*CCC + c0);
    float s = qf[0]*bfl(ka.x) + qf[1]*bfh(ka.x)
            + qf[2]*bfl(ka.y) + qf[3]*bfh(ka.y)
            + qf[4]*bfl(ka.z) + qf[5]*bfh(ka.z)
            + qf[6]*bfl(ka.w) + qf[7]*bfh(ka.w);
    #pragma unroll
    for (int off = 8; off; off >>= 1) s += __shfl_xor(s, off);
    float p = expf((s + eav * qw) * SCALE);
    uint4 va = *(const uint4*)(qkvs + (size_t)src*QS + 1024 + h*CCC + c0);
    accv[0] += p*bfl(va.x); accv[1] += p*bfh(va.x);
    accv[2] += p*bfl(va.y); accv[3] += p*bfh(va.y);
    accv[4] += p*bfl(va.z); accv[5] += p*bfh(va.z);
    accv[6] += p*bfl(va.w); accv[7] += p*bfh(va.w);
    accp += p; accw += p*eav;
  }

  float inv = 1.f / (accp + 1e-16f);
  float se  = accw * inv;
  u16* ap = qkvs + (size_t)n*QS + 1536 + h*CCC + c0;
  *(uint4*)ap = make_uint4(
    pack2(accv[0]*inv+se*wf[0], accv[1]*inv+se*wf[1]),
    pack2(accv[2]*inv+se*wf[2], accv[3]*inv+se*wf[3]),
    pack2(accv[4]*inv+se*wf[4], accv[5]*inv+se*wf[5]),
    pack2(accv[6]*inv+se*wf[6], accv[7]*inv+se*wf[7]));
}

// K4: h = elu(conv@Wp + x@Wskp + bpe) ; y = x + h ; LayerNorm (in-register)
// ONE WAVE per 16 rows (64-thread blocks) for latency tolerance via occupancy.
__global__ __launch_bounds__(64) void k4_mfma(
    const u16* __restrict__ qkvs, const u16* __restrict__ Wpt,
    const u16* __restrict__ Wskt, const float* __restrict__ bpe,
    const float* __restrict__ gamma, const float* __restrict__ beta,
    const float* x_in, float* x_out)
{
  __shared__ float yt[16][132];
  const int lane = threadIdx.x & 63;
  const int lo = lane & 15, hi = lane >> 4;
  const int r0 = blockIdx.x * 16;
  const int row = r0 + lo;

  fx4 acc[8] = {};

  // skip pass: A = x rows (bf16 on the fly), B = Wskt, K=128
  {
    const float* xp = x_in + (size_t)row*HIDD;
    bfrag af[4];
    #pragma unroll
    for (int s = 0; s < 4; ++s) {
      bfcvt cv;
      if (row < NN) {
        float4 u = *(const float4*)(xp + s*32 + hi*8);
        float4 w = *(const float4*)(xp + s*32 + hi*8 + 4);
        cv.u = make_uint4(pack2(u.x,u.y), pack2(u.z,u.w),
                          pack2(w.x,w.y), pack2(w.z,w.w));
      } else {
        cv.u = make_uint4(0u,0u,0u,0u);
      }
      af[s] = cv.f;
    }
    #pragma unroll
    for (int s = 0; s < 4; ++s)
      #pragma unroll
      for (int c = 0; c < 8; ++c) {
        bfrag b = *(const bfrag*)(Wskt + (size_t)(c*16 + lo)*128 + s*32 + hi*8);
        acc[c] = __builtin_amdgcn_mfma_f32_16x16x32_bf16(af[s], b, acc[c], 0, 0, 0);
      }
  }

  // conv passes: K=512 in 4 head chunks; A-frags prefetched per chunk
  const u16* cp = qkvs + (size_t)row*QS + 1536;
  #pragma unroll
  for (int h = 0; h < 4; ++h) {
    bfrag af[4];
    #pragma unroll
    for (int s = 0; s < 4; ++s) {
      bfcvt cv;
      if (row < NN) cv.u = *(const uint4*)(cp + h*CCC + s*32 + hi*8);
      else          cv.u = make_uint4(0u,0u,0u,0u);
      af[s] = cv.f;
    }
    #pragma unroll
    for (int s = 0; s < 4; ++s)
      #pragma unroll
      for (int c = 0; c < 8; ++c) {
        bfrag b = *(const bfrag*)(Wpt + (size_t)(c*16 + lo)*512 + h*128 + s*32 + hi*8);
        acc[c] = __builtin_amdgcn_mfma_f32_16x16x32_bf16(af[s], b, acc[c], 0, 0, 0);
      }
  }

  // epilogue: bias + ELU + residual, in-register LayerNorm
  const int rbase = r0 + hi*4;
  float y[8][4];
  #pragma unroll
  for (int c = 0; c < 8; ++c) {
    float bb = bpe[c*16 + lo];
    #pragma unroll
    for (int j = 0; j < 4; ++j) {
      int rr = rbase + j;
      float v = acc[c][j] + bb;
      v = v > 0.f ? v : expm1f(v);
      float xv = (rr < NN) ? x_in[(size_t)rr*HIDD + c*16 + lo] : 0.f;
      y[c][j] = xv + v;
    }
  }
  float mu[4], rs[4];
  #pragma unroll
  for (int j = 0; j < 4; ++j) {
    float s = 0.f, s2 = 0.f;
    #pragma unroll
    for (int c = 0; c < 8; ++c) { s += y[c][j]; s2 += y[c][j]*y[c][j]; }
    #pragma unroll
    for (int off = 8; off; off >>= 1) { s += __shfl_xor(s, off); s2 += __shfl_xor(s2, off); }
    mu[j] = s * (1.f/128.f);
    float var = s2 * (1.f/128.f) - mu[j]*mu[j];
    rs[j] = rsqrtf(var + 1e-5f);
  }

  // normalized values -> LDS (single wave; no barrier) -> coalesced stores
  #pragma unroll
  for (int c = 0; c < 8; ++c) {
    float g  = gamma[c*16 + lo];
    float bt = beta[c*16 + lo];
    #pragma unroll
    for (int j = 0; j < 4; ++j)
      yt[hi*4 + j][c*16 + lo] = (y[c][j] - mu[j])*rs[j]*g + bt;
  }
  #pragma unroll
  for (int i = 0; i < 8; ++i) {
    int f = lane + 64*i;           // 16*128/4 = 512 float4
    int r = f >> 5, c4 = (f & 31) * 4;
    int rr = r0 + r;
    if (rr < NN)
      *(float4*)(x_out + (size_t)rr*HIDD + c4) = *(float4*)&yt[r][c4];
  }
}

extern "C" void kernel_launch(void* const* d_in, const int* in_sizes, int n_in,
                              void* d_out, int out_size, void* d_ws, size_t ws_size,
                              hipStream_t stream)
{
  const float* x    = (const float*)d_in[0];
  const int*   ei   = (const int*)d_in[1];
  const float* ea   = (const float*)d_in[2];
  const float* Wq   = (const float*)d_in[3];
  const float* bq   = (const float*)d_in[4];
  const float* Wk   = (const float*)d_in[5];
  const float* bk   = (const float*)d_in[6];
  const float* Wv   = (const float*)d_in[7];
  const float* bv   = (const float*)d_in[8];
  const float* We   = (const float*)d_in[9];
  const float* Wsk  = (const float*)d_in[10];
  const float* bsk  = (const float*)d_in[11];
  const float* Wp   = (const float*)d_in[12];
  const float* bp   = (const float*)d_in[13];
  const float* gamma= (const float*)d_in[14];
  const float* beta = (const float*)d_in[15];

  char* wsb = (char*)d_ws;
  size_t off = 0;
  auto alloc = [&](size_t bytes) -> void* {
    void* p = wsb + off;
    off += (bytes + 255) & ~(size_t)255;
    return p;
  };
  u16*   qkvs    = (u16*)  alloc((size_t)NN*QS*2);     // 204.8 MB (q|k|v|conv)
  int*   rowptr  = (int*)  alloc((size_t)(NN+1)*4);
  int*   counts  = (int*)  alloc((size_t)NN*4);
  int*   fill    = (int*)  alloc((size_t)NN*4);
  int*   bsum    = (int*)  alloc((size_t)256*4);
  int*   csr_src = (int*)  alloc((size_t)EE*4);
  float* csr_ea  = (float*)alloc((size_t)EE*4);
  u16*   Wt      = (u16*)  alloc((size_t)1536*128*2);
  u16*   Wpt     = (u16*)  alloc((size_t)128*512*2);
  u16*   Wskt    = (u16*)  alloc((size_t)128*128*2);
  float* biasc   = (float*)alloc((size_t)1536*4);
  float* bpe     = (float*)alloc((size_t)128*4);
  float* xio     = (float*)d_out;

  const int gn  = (NN + 255)/256;     // 196
  const int ge  = (EE + 255)/256;
  const int gp  = (1536*128 + 128*512 + 1536 + 255)/256;
  const int g1  = (NN + 63)/64;       // 782
  const int g23 = (NN + 3)/4;
  const int g4  = (NN + 15)/16;       // 3125 one-wave blocks

  // ---- CSR build (graph constant across layers) ----
  kzero<<<gn, 256, 0, stream>>>(counts, NN);
  kzero<<<gn, 256, 0, stream>>>(fill, NN);
  khist<<<ge, 256, 0, stream>>>(ei, counts);
  kscanA<<<gn, 256, 0, stream>>>(counts, bsum);
  kscanB<<<1, 256, 0, stream>>>(bsum, gn);
  kscanC<<<gn, 256, 0, stream>>>(counts, bsum, rowptr);
  kscatter<<<ge, 256, 0, stream>>>(ei, ea, rowptr, fill, csr_src, csr_ea);

  for (int l = 0; l < LLL; ++l) {
    const float* Wq_l  = Wq  + (size_t)l*HIDD*HCC;
    const float* Wk_l  = Wk  + (size_t)l*HIDD*HCC;
    const float* Wv_l  = Wv  + (size_t)l*HIDD*HCC;
    const float* Wsk_l = Wsk + (size_t)l*HIDD*HCC;
    const float* bq_l  = bq  + (size_t)l*HCC;
    const float* bk_l  = bk  + (size_t)l*HCC;
    const float* bv_l  = bv  + (size_t)l*HCC;
    const float* bsk_l = bsk + (size_t)l*HCC;
    const float* We_l  = We  + (size_t)l*HCC;
    const float* Wp_l  = Wp  + (size_t)l*HCC*HIDD;
    const float* bp_l  = bp  + (size_t)l*HIDD;
    const float* g_l   = gamma + (size_t)l*HIDD;
    const float* b_l   = beta  + (size_t)l*HIDD;

    const float* xin = (l == 0) ? x : xio;

    kprep<<<gp, 256, 0, stream>>>(Wq_l, Wk_l, Wv_l, bq_l, bk_l, bv_l,
                                  Wp_l, Wt, Wpt, biasc);
    kskp<<<129, 256, 0, stream>>>(Wsk_l, bsk_l, Wp_l, bp_l, Wskt, bpe);
    k1_mfma<<<g1, 256, 0, stream>>>(xin, Wt, biasc, qkvs);
    k23_fused<<<g23, 256, 0, stream>>>(qkvs, rowptr, csr_src, csr_ea, We_l);
    k4_mfma<<<g4, 64, 0, stream>>>(qkvs, Wpt, Wskt, bpe, g_l, b_l, xin, xio);
  }
}